// Round 1
// baseline (2595.937 us; speedup 1.0000x reference)
//
#include <hip/hip_runtime.h>
#include <hip/hip_bf16.h>
#include <math.h>

#define T_TOK 2048
#define H_DIM 768
#define E_NUM 8
#define K_TOP 2
#define DF_DIM 3072
#define L_NUM 2
#define LN_EPS 1e-5f
#define NPAIR (T_TOK * K_TOP)

// ---------------- embedding gather ----------------
__global__ void gather_embed(const int* __restrict__ ids,
                             const float* __restrict__ embed,
                             float* __restrict__ x) {
    int idx = blockIdx.x * blockDim.x + threadIdx.x;      // float4 index
    int total = T_TOK * H_DIM / 4;
    if (idx >= total) return;
    int row = idx / (H_DIM / 4);
    int col = idx % (H_DIM / 4);
    const float4* src = (const float4*)(embed + (size_t)ids[row] * H_DIM);
    ((float4*)(x + (size_t)row * H_DIM))[col] = src[col];
}

// ---------------- LN + gate (one block per token) ----------------
__global__ __launch_bounds__(256) void ln_gate(
    const float* __restrict__ x, const float* __restrict__ g, const float* __restrict__ b,
    const float* __restrict__ gw, const float* __restrict__ gb,
    float* __restrict__ flat, int* __restrict__ topi, float* __restrict__ topw,
    int* __restrict__ cnt, float* __restrict__ probs_sum, float* __restrict__ counts_out)
{
    int t = blockIdx.x;
    int tid = threadIdx.x;
    const float* xr = x + (size_t)t * H_DIM;
    __shared__ float s[H_DIM];
    __shared__ float red[8];
    __shared__ float logits_s[E_NUM];

    float v0 = xr[tid], v1 = xr[tid + 256], v2 = xr[tid + 512];
    float sum = v0 + v1 + v2;
    #pragma unroll
    for (int o = 32; o > 0; o >>= 1) sum += __shfl_down(sum, o);
    int wave = tid >> 6, lane = tid & 63;
    if (lane == 0) red[wave] = sum;
    __syncthreads();
    if (tid == 0) red[4] = (red[0] + red[1] + red[2] + red[3]) * (1.0f / H_DIM);
    __syncthreads();
    float mean = red[4];

    float d0 = v0 - mean, d1 = v1 - mean, d2 = v2 - mean;
    float ss = d0 * d0 + d1 * d1 + d2 * d2;
    #pragma unroll
    for (int o = 32; o > 0; o >>= 1) ss += __shfl_down(ss, o);
    if (lane == 0) red[wave] = ss;
    __syncthreads();
    if (tid == 0) red[4] = rsqrtf((red[0] + red[1] + red[2] + red[3]) * (1.0f / H_DIM) + LN_EPS);
    __syncthreads();
    float inv = red[4];

    float n0 = d0 * inv * g[tid]       + b[tid];
    float n1 = d1 * inv * g[tid + 256] + b[tid + 256];
    float n2 = d2 * inv * g[tid + 512] + b[tid + 512];
    s[tid] = n0; s[tid + 256] = n1; s[tid + 512] = n2;
    float* fr = flat + (size_t)t * H_DIM;
    fr[tid] = n0; fr[tid + 256] = n1; fr[tid + 512] = n2;
    __syncthreads();

    // logits: wave w handles experts 2w, 2w+1
    for (int e = wave * 2; e < wave * 2 + 2; ++e) {
        float p = 0.0f;
        const float* wrow = gw + (size_t)e * H_DIM;
        for (int j = lane; j < H_DIM; j += 64) p += s[j] * wrow[j];
        #pragma unroll
        for (int o = 32; o > 0; o >>= 1) p += __shfl_down(p, o);
        if (lane == 0) logits_s[e] = p + gb[e];
    }
    __syncthreads();

    if (tid == 0) {
        float lg[E_NUM];
        #pragma unroll
        for (int e = 0; e < E_NUM; e++) lg[e] = logits_s[e];
        int i0 = 0; float m0 = lg[0];
        #pragma unroll
        for (int e = 1; e < E_NUM; e++) if (lg[e] > m0) { m0 = lg[e]; i0 = e; }
        int i1 = -1; float m1 = -1e30f;
        #pragma unroll
        for (int e = 0; e < E_NUM; e++) if (e != i0 && lg[e] > m1) { m1 = lg[e]; i1 = e; }
        float e1 = expf(m1 - m0);
        float inv_s = 1.0f / (1.0f + e1);
        float w0 = inv_s, w1 = e1 * inv_s;
        topi[t * 2] = i0; topi[t * 2 + 1] = i1;
        topw[t * 2] = w0; topw[t * 2 + 1] = w1;
        atomicAdd(&cnt[i0], 1); atomicAdd(&cnt[i1], 1);
        atomicAdd(&counts_out[i0], 1.0f); atomicAdd(&counts_out[i1], 1.0f);
        // full softmax for l_aux
        float m8 = lg[0];
        #pragma unroll
        for (int e = 1; e < E_NUM; e++) m8 = fmaxf(m8, lg[e]);
        float pe[E_NUM]; float sm = 0.0f;
        #pragma unroll
        for (int e = 0; e < E_NUM; e++) { pe[e] = expf(lg[e] - m8); sm += pe[e]; }
        float isv = 1.0f / sm;
        #pragma unroll
        for (int e = 0; e < E_NUM; e++) atomicAdd(&probs_sum[e], pe[e] * isv);
    }
}

// ---------------- offsets scan + l_aux ----------------
__global__ void offsets_laux(const int* __restrict__ cnt, int* __restrict__ offs,
                             const float* __restrict__ probs_sum, float* __restrict__ laux) {
    if (blockIdx.x == 0 && threadIdx.x == 0) {
        int run = 0;
        for (int e = 0; e < E_NUM; e++) { offs[e] = run; run += cnt[e]; }
        float la = 0.0f;
        for (int e = 0; e < E_NUM; e++) {
            float p = probs_sum[e] * (1.0f / T_TOK);
            la += p * p;
        }
        atomicAdd(laux, la * E_NUM);
    }
}

// ---------------- pair compaction ----------------
__global__ void scatter_pairs(const int* __restrict__ topi, const float* __restrict__ topw,
                              const int* __restrict__ offs, int* __restrict__ fill,
                              int* __restrict__ pair_tok, float* __restrict__ pair_w) {
    int t = blockIdx.x * blockDim.x + threadIdx.x;
    if (t >= T_TOK) return;
    #pragma unroll
    for (int k = 0; k < K_TOP; k++) {
        int e = topi[t * 2 + k];
        int pos = atomicAdd(&fill[e], 1);
        int p = offs[e] + pos;
        pair_tok[p] = t;
        pair_w[p] = topw[t * 2 + k];
    }
}

// ---------------- fc1 GEMM: h1[p] = gelu(flat[tok(p)] @ W1[e]^T + b1[e]) ----------------
__global__ __launch_bounds__(256) void fc1_gemm(
    const float* __restrict__ flat, const float* __restrict__ w1, const float* __restrict__ b1,
    const int* __restrict__ cnt, const int* __restrict__ offs,
    const int* __restrict__ pair_tok, float* __restrict__ h1)
{
    int e = blockIdx.z;
    int c = cnt[e];
    int m0 = blockIdx.y * 64;
    if (m0 >= c) return;
    int n0 = blockIdx.x * 64;
    int seg = offs[e];
    const float* W = w1 + (size_t)e * DF_DIM * H_DIM;

    __shared__ float As[16][65];
    __shared__ float Bs[16][65];
    __shared__ int rowtok[64];

    int tid = threadIdx.x;
    if (tid < 64) {
        int m = m0 + tid;
        rowtok[tid] = (m < c) ? pair_tok[seg + m] : pair_tok[seg];
    }
    __syncthreads();

    int tx = tid & 15, ty = tid >> 4;
    int lr = tid >> 2, lk = (tid & 3) * 4;
    const float* arow = flat + (size_t)rowtok[lr] * H_DIM;
    const float* brow = W + (size_t)(n0 + lr) * H_DIM;

    float acc[4][4] = {};
    for (int k0 = 0; k0 < H_DIM; k0 += 16) {
        float4 a  = *(const float4*)(arow + k0 + lk);
        float4 bv = *(const float4*)(brow + k0 + lk);
        As[lk + 0][lr] = a.x;  As[lk + 1][lr] = a.y;  As[lk + 2][lr] = a.z;  As[lk + 3][lr] = a.w;
        Bs[lk + 0][lr] = bv.x; Bs[lk + 1][lr] = bv.y; Bs[lk + 2][lr] = bv.z; Bs[lk + 3][lr] = bv.w;
        __syncthreads();
        #pragma unroll
        for (int k = 0; k < 16; k++) {
            float av[4], bw[4];
            #pragma unroll
            for (int i = 0; i < 4; i++) av[i] = As[k][ty * 4 + i];
            #pragma unroll
            for (int j = 0; j < 4; j++) bw[j] = Bs[k][tx * 4 + j];
            #pragma unroll
            for (int i = 0; i < 4; i++)
                #pragma unroll
                for (int j = 0; j < 4; j++) acc[i][j] += av[i] * bw[j];
        }
        __syncthreads();
    }

    #pragma unroll
    for (int i = 0; i < 4; i++) {
        int m = m0 + ty * 4 + i;
        if (m >= c) continue;
        int p = seg + m;
        float* out = h1 + (size_t)p * DF_DIM + n0;
        #pragma unroll
        for (int j = 0; j < 4; j++) {
            int n = tx * 4 + j;
            float v = acc[i][j] + b1[e * DF_DIM + n0 + n];
            out[n] = 0.5f * v * (1.0f + erff(v * 0.70710678118f));
        }
    }
}

// ---------------- fc2 GEMM: x[tok(p)] += w_p * (h1[p] @ W2[e]^T + b2[e]) ----------------
__global__ __launch_bounds__(256) void fc2_gemm(
    const float* __restrict__ h1, const float* __restrict__ w2, const float* __restrict__ b2,
    const int* __restrict__ cnt, const int* __restrict__ offs,
    const int* __restrict__ pair_tok, const float* __restrict__ pair_w,
    float* __restrict__ x)
{
    int e = blockIdx.z;
    int c = cnt[e];
    int m0 = blockIdx.y * 64;
    if (m0 >= c) return;
    int n0 = blockIdx.x * 64;
    int seg = offs[e];
    const float* W = w2 + (size_t)e * H_DIM * DF_DIM;

    __shared__ float As[16][65];
    __shared__ float Bs[16][65];

    int tid = threadIdx.x;
    int tx = tid & 15, ty = tid >> 4;
    int lr = tid >> 2, lk = (tid & 3) * 4;
    int ar = m0 + lr; if (ar > c - 1) ar = c - 1;
    const float* arow = h1 + (size_t)(seg + ar) * DF_DIM;
    const float* brow = W + (size_t)(n0 + lr) * DF_DIM;

    float acc[4][4] = {};
    for (int k0 = 0; k0 < DF_DIM; k0 += 16) {
        float4 a  = *(const float4*)(arow + k0 + lk);
        float4 bv = *(const float4*)(brow + k0 + lk);
        As[lk + 0][lr] = a.x;  As[lk + 1][lr] = a.y;  As[lk + 2][lr] = a.z;  As[lk + 3][lr] = a.w;
        Bs[lk + 0][lr] = bv.x; Bs[lk + 1][lr] = bv.y; Bs[lk + 2][lr] = bv.z; Bs[lk + 3][lr] = bv.w;
        __syncthreads();
        #pragma unroll
        for (int k = 0; k < 16; k++) {
            float av[4], bw[4];
            #pragma unroll
            for (int i = 0; i < 4; i++) av[i] = As[k][ty * 4 + i];
            #pragma unroll
            for (int j = 0; j < 4; j++) bw[j] = Bs[k][tx * 4 + j];
            #pragma unroll
            for (int i = 0; i < 4; i++)
                #pragma unroll
                for (int j = 0; j < 4; j++) acc[i][j] += av[i] * bw[j];
        }
        __syncthreads();
    }

    #pragma unroll
    for (int i = 0; i < 4; i++) {
        int m = m0 + ty * 4 + i;
        if (m >= c) continue;
        int p = seg + m;
        int t = pair_tok[p];
        float wp = pair_w[p];
        float* xr = x + (size_t)t * H_DIM + n0;
        #pragma unroll
        for (int j = 0; j < 4; j++) {
            int n = tx * 4 + j;
            atomicAdd(&xr[n], wp * (acc[i][j] + b2[e * H_DIM + n0 + n]));
        }
    }
}

extern "C" void kernel_launch(void* const* d_in, const int* in_sizes, int n_in,
                              void* d_out, int out_size, void* d_ws, size_t ws_size,
                              hipStream_t stream) {
    const int*   ids    = (const int*)d_in[0];
    const float* embed  = (const float*)d_in[1];
    const float* ln_g   = (const float*)d_in[2];
    const float* ln_b   = (const float*)d_in[3];
    const float* gate_w = (const float*)d_in[4];
    const float* gate_b = (const float*)d_in[5];
    const float* fc1_w  = (const float*)d_in[6];
    const float* fc1_b  = (const float*)d_in[7];
    const float* fc2_w  = (const float*)d_in[8];
    const float* fc2_b  = (const float*)d_in[9];

    float* x      = (float*)d_out;              // [T,H] residual stream lives in d_out
    float* laux   = x + (size_t)T_TOK * H_DIM;  // 1
    float* counts = laux + 1;                   // 8

    float* ws       = (float*)d_ws;
    float* flat     = ws;                                        // T*H
    float* h1       = flat + (size_t)T_TOK * H_DIM;              // NPAIR*DF
    int*   pair_tok = (int*)(h1 + (size_t)NPAIR * DF_DIM);       // NPAIR
    float* pair_w   = (float*)(pair_tok + NPAIR);                // NPAIR
    int*   cnt      = (int*)(pair_w + NPAIR);                    // 8
    int*   offs     = cnt + E_NUM;                               // 8
    int*   fill     = offs + E_NUM;                              // 8
    float* probs    = (float*)(fill + E_NUM);                    // 8
    int*   topi     = (int*)(probs + E_NUM);                     // T*2
    float* topw     = (float*)(topi + T_TOK * K_TOP);            // T*2

    // zero l_aux + counts (harness does not re-poison between replays)
    hipMemsetAsync(laux, 0, 9 * sizeof(float), stream);

    gather_embed<<<(T_TOK * H_DIM / 4 + 255) / 256, 256, 0, stream>>>(ids, embed, x);

    for (int l = 0; l < L_NUM; l++) {
        hipMemsetAsync(cnt, 0, 4 * E_NUM * sizeof(int), stream);  // cnt, offs, fill, probs
        ln_gate<<<T_TOK, 256, 0, stream>>>(
            x, ln_g + l * H_DIM, ln_b + l * H_DIM,
            gate_w + (size_t)l * E_NUM * H_DIM, gate_b + l * E_NUM,
            flat, topi, topw, cnt, probs, counts);
        offsets_laux<<<1, 64, 0, stream>>>(cnt, offs, probs, laux);
        scatter_pairs<<<(T_TOK + 255) / 256, 256, 0, stream>>>(topi, topw, offs, fill, pair_tok, pair_w);
        dim3 g1(DF_DIM / 64, (T_TOK + 63) / 64, E_NUM);
        fc1_gemm<<<g1, 256, 0, stream>>>(
            flat, fc1_w + (size_t)l * E_NUM * DF_DIM * H_DIM,
            fc1_b + (size_t)l * E_NUM * DF_DIM, cnt, offs, pair_tok, h1);
        dim3 g2(H_DIM / 64, (T_TOK + 63) / 64, E_NUM);
        fc2_gemm<<<g2, 256, 0, stream>>>(
            h1, fc2_w + (size_t)l * E_NUM * H_DIM * DF_DIM,
            fc2_b + (size_t)l * E_NUM * H_DIM, cnt, offs, pair_tok, pair_w, x);
    }
}

// Round 2
// 975.345 us; speedup vs baseline: 2.6616x; 2.6616x over previous
//
#include <hip/hip_runtime.h>
#include <hip/hip_bf16.h>
#include <math.h>

#define T_TOK 2048
#define H_DIM 768
#define E_NUM 8
#define K_TOP 2
#define DF_DIM 3072
#define L_NUM 2
#define LN_EPS 1e-5f
#define NPAIR (T_TOK * K_TOP)

typedef __hip_bfloat16 bf16;
typedef __attribute__((ext_vector_type(8))) short bf16x8;   // 8 bf16 = 4 VGPRs
typedef __attribute__((ext_vector_type(4))) float f32x4;

// ---------------- embedding gather ----------------
__global__ void gather_embed(const int* __restrict__ ids,
                             const float* __restrict__ embed,
                             float* __restrict__ x) {
    int idx = blockIdx.x * blockDim.x + threadIdx.x;
    int total = T_TOK * H_DIM / 4;
    if (idx >= total) return;
    int row = idx / (H_DIM / 4);
    int col = idx % (H_DIM / 4);
    const float4* src = (const float4*)(embed + (size_t)ids[row] * H_DIM);
    ((float4*)(x + (size_t)row * H_DIM))[col] = src[col];
}

// ---------------- f32 -> bf16 weight conversion ----------------
__global__ __launch_bounds__(256) void conv_bf16(const float* __restrict__ src,
                                                 bf16* __restrict__ dst, int n8) {
    int i = blockIdx.x * blockDim.x + threadIdx.x;
    if (i >= n8) return;
    float4 a = ((const float4*)src)[i * 2];
    float4 b = ((const float4*)src)[i * 2 + 1];
    union { bf16 h[8]; uint4 u; } p;
    p.h[0] = __float2bfloat16(a.x); p.h[1] = __float2bfloat16(a.y);
    p.h[2] = __float2bfloat16(a.z); p.h[3] = __float2bfloat16(a.w);
    p.h[4] = __float2bfloat16(b.x); p.h[5] = __float2bfloat16(b.y);
    p.h[6] = __float2bfloat16(b.z); p.h[7] = __float2bfloat16(b.w);
    ((uint4*)dst)[i] = p.u;
}

// ---------------- LN + gate (one block per token) ----------------
__global__ __launch_bounds__(256) void ln_gate(
    const float* __restrict__ x, const float* __restrict__ g, const float* __restrict__ b,
    const float* __restrict__ gw, const float* __restrict__ gb,
    bf16* __restrict__ flat, int* __restrict__ topi, float* __restrict__ topw,
    int* __restrict__ cnt, float* __restrict__ probs_sum, float* __restrict__ counts_out)
{
    int t = blockIdx.x;
    int tid = threadIdx.x;
    const float* xr = x + (size_t)t * H_DIM;
    __shared__ float s[H_DIM];
    __shared__ float red[8];
    __shared__ float logits_s[E_NUM];

    float v0 = xr[tid], v1 = xr[tid + 256], v2 = xr[tid + 512];
    float sum = v0 + v1 + v2;
    #pragma unroll
    for (int o = 32; o > 0; o >>= 1) sum += __shfl_down(sum, o);
    int wave = tid >> 6, lane = tid & 63;
    if (lane == 0) red[wave] = sum;
    __syncthreads();
    if (tid == 0) red[4] = (red[0] + red[1] + red[2] + red[3]) * (1.0f / H_DIM);
    __syncthreads();
    float mean = red[4];

    float d0 = v0 - mean, d1 = v1 - mean, d2 = v2 - mean;
    float ss = d0 * d0 + d1 * d1 + d2 * d2;
    #pragma unroll
    for (int o = 32; o > 0; o >>= 1) ss += __shfl_down(ss, o);
    if (lane == 0) red[wave] = ss;
    __syncthreads();
    if (tid == 0) red[4] = rsqrtf((red[0] + red[1] + red[2] + red[3]) * (1.0f / H_DIM) + LN_EPS);
    __syncthreads();
    float inv = red[4];

    float n0 = d0 * inv * g[tid]       + b[tid];
    float n1 = d1 * inv * g[tid + 256] + b[tid + 256];
    float n2 = d2 * inv * g[tid + 512] + b[tid + 512];
    s[tid] = n0; s[tid + 256] = n1; s[tid + 512] = n2;
    bf16* fr = flat + (size_t)t * H_DIM;
    fr[tid] = __float2bfloat16(n0);
    fr[tid + 256] = __float2bfloat16(n1);
    fr[tid + 512] = __float2bfloat16(n2);
    __syncthreads();

    for (int e = wave * 2; e < wave * 2 + 2; ++e) {
        float p = 0.0f;
        const float* wrow = gw + (size_t)e * H_DIM;
        for (int j = lane; j < H_DIM; j += 64) p += s[j] * wrow[j];
        #pragma unroll
        for (int o = 32; o > 0; o >>= 1) p += __shfl_down(p, o);
        if (lane == 0) logits_s[e] = p + gb[e];
    }
    __syncthreads();

    if (tid == 0) {
        float lg[E_NUM];
        #pragma unroll
        for (int e = 0; e < E_NUM; e++) lg[e] = logits_s[e];
        int i0 = 0; float m0 = lg[0];
        #pragma unroll
        for (int e = 1; e < E_NUM; e++) if (lg[e] > m0) { m0 = lg[e]; i0 = e; }
        int i1 = -1; float m1 = -1e30f;
        #pragma unroll
        for (int e = 0; e < E_NUM; e++) if (e != i0 && lg[e] > m1) { m1 = lg[e]; i1 = e; }
        float e1 = expf(m1 - m0);
        float inv_s = 1.0f / (1.0f + e1);
        topi[t * 2] = i0; topi[t * 2 + 1] = i1;
        topw[t * 2] = inv_s; topw[t * 2 + 1] = e1 * inv_s;
        atomicAdd(&cnt[i0], 1); atomicAdd(&cnt[i1], 1);
        atomicAdd(&counts_out[i0], 1.0f); atomicAdd(&counts_out[i1], 1.0f);
        float m8 = lg[0];
        #pragma unroll
        for (int e = 1; e < E_NUM; e++) m8 = fmaxf(m8, lg[e]);
        float pe[E_NUM]; float sm = 0.0f;
        #pragma unroll
        for (int e = 0; e < E_NUM; e++) { pe[e] = expf(lg[e] - m8); sm += pe[e]; }
        float isv = 1.0f / sm;
        #pragma unroll
        for (int e = 0; e < E_NUM; e++) atomicAdd(&probs_sum[e], pe[e] * isv);
    }
}

// ---------------- offsets scan + l_aux ----------------
__global__ void offsets_laux(const int* __restrict__ cnt, int* __restrict__ offs,
                             const float* __restrict__ probs_sum, float* __restrict__ laux) {
    if (blockIdx.x == 0 && threadIdx.x == 0) {
        int run = 0;
        for (int e = 0; e < E_NUM; e++) { offs[e] = run; run += cnt[e]; }
        float la = 0.0f;
        for (int e = 0; e < E_NUM; e++) {
            float p = probs_sum[e] * (1.0f / T_TOK);
            la += p * p;
        }
        atomicAdd(laux, la * E_NUM);
    }
}

// ---------------- pair compaction + inverse map ----------------
__global__ void scatter_pairs(const int* __restrict__ topi,
                              const int* __restrict__ offs, int* __restrict__ fill,
                              int* __restrict__ pair_tok, int* __restrict__ inv) {
    int t = blockIdx.x * blockDim.x + threadIdx.x;
    if (t >= T_TOK) return;
    #pragma unroll
    for (int k = 0; k < K_TOP; k++) {
        int e = topi[t * 2 + k];
        int pos = atomicAdd(&fill[e], 1);
        int p = offs[e] + pos;
        pair_tok[p] = t;
        inv[t * 2 + k] = p;
    }
}

// ---------------- MFMA grouped GEMM ----------------
// MODE 0 (fc1): A = flat[pair_tok[row]] (bf16), out = h1 bf16 with bias+GELU
// MODE 1 (fc2): A = h1[seg+row] (bf16),      out = out_pairs f32 with bias
// tile: BM=128 x BN=32*NF, BK=32. 4 waves as 2(M) x 2(N), wave = 64 x 16*NF.
template<int NF, int MODE, int KDIM, int NTOT>
__global__ __launch_bounds__(256) void moe_gemm(
    const bf16* __restrict__ Abase, const bf16* __restrict__ Wbase,
    const float* __restrict__ bias,
    const int* __restrict__ cnt, const int* __restrict__ offs,
    const int* __restrict__ pair_tok, void* __restrict__ outp)
{
    constexpr int BM = 128;
    constexpr int BN = 32 * NF;
    constexpr int NISS = (BM + BN) / 16;   // 1KB staging issues per K-step
    constexpr int IPW  = NISS / 4;         // issues per wave

    int e = blockIdx.z;
    int c = cnt[e];
    int m0 = blockIdx.y * BM;
    if (m0 >= c) return;
    int n0 = blockIdx.x * BN;
    int seg = offs[e];
    const bf16* W = Wbase + (size_t)e * NTOT * KDIM;

    __shared__ char smem[(BM + BN) * 64];  // A tile [128][32]bf16, B tile [BN][32]bf16, swizzled

    int tid = threadIdx.x;
    int lane = tid & 63, wv = tid >> 6;

    // ---- per-lane staging setup (fixed across K loop) ----
    const bf16* gb[IPW];
    int ldsoff[IPW];
    #pragma unroll
    for (int q = 0; q < IPW; q++) {
        int j = wv + q * 4;                // issue id 0..NISS-1
        int rloc = lane >> 2;              // 16 rows per issue
        int kb = lane & 3;                 // 4 chunks of 8 bf16 per row
        int row, base;
        const bf16* g;
        if (j < 8) {                       // A rows
            row = j * 16 + rloc;
            int m = m0 + row;
            int mm = (m < c) ? m : (c - 1);
            if (MODE == 0)
                g = Abase + (size_t)pair_tok[seg + mm] * KDIM + kb * 8;
            else
                g = Abase + (size_t)(seg + mm) * KDIM + kb * 8;
            base = 0;
        } else {                           // B rows
            row = (j - 8) * 16 + rloc;
            g = W + (size_t)(n0 + row) * KDIM + kb * 8;
            base = BM * 64;
        }
        gb[q] = g;
        int line = row >> 1;
        int cc = ((row & 1) << 2) | kb;
        ldsoff[q] = base + line * 128 + ((cc ^ (line & 7)) << 4);
    }

    // ---- per-lane fragment read offsets ----
    int wm = wv >> 1, wn = wv & 1;
    int aoff[4], boff[NF];
    {
        int kb = lane >> 4;
        #pragma unroll
        for (int mf = 0; mf < 4; mf++) {
            int row = wm * 64 + mf * 16 + (lane & 15);
            int line = row >> 1;
            int cc = ((row & 1) << 2) | kb;
            aoff[mf] = line * 128 + ((cc ^ (line & 7)) << 4);
        }
        #pragma unroll
        for (int nf = 0; nf < NF; nf++) {
            int row = wn * NF * 16 + nf * 16 + (lane & 15);
            int line = row >> 1;
            int cc = ((row & 1) << 2) | kb;
            boff[nf] = BM * 64 + line * 128 + ((cc ^ (line & 7)) << 4);
        }
    }

    f32x4 acc[4][NF];
    #pragma unroll
    for (int i = 0; i < 4; i++)
        #pragma unroll
        for (int j = 0; j < NF; j++) acc[i][j] = (f32x4){0.f, 0.f, 0.f, 0.f};

    // ---- K loop (2-barrier) ----
    for (int k0 = 0; k0 < KDIM; k0 += 32) {
        uint4 v[IPW];
        #pragma unroll
        for (int q = 0; q < IPW; q++) v[q] = *(const uint4*)(gb[q] + k0);
        #pragma unroll
        for (int q = 0; q < IPW; q++) *(uint4*)(smem + ldsoff[q]) = v[q];
        __syncthreads();
        bf16x8 af[4], bfr[NF];
        #pragma unroll
        for (int mf = 0; mf < 4; mf++) af[mf] = *(const bf16x8*)(smem + aoff[mf]);
        #pragma unroll
        for (int nf = 0; nf < NF; nf++) bfr[nf] = *(const bf16x8*)(smem + boff[nf]);
        #pragma unroll
        for (int mf = 0; mf < 4; mf++)
            #pragma unroll
            for (int nf = 0; nf < NF; nf++)
                acc[mf][nf] = __builtin_amdgcn_mfma_f32_16x16x32_bf16(af[mf], bfr[nf], acc[mf][nf], 0, 0, 0);
        __syncthreads();
    }

    // ---- epilogue (C layout: col = lane&15, row = (lane>>4)*4 + i) ----
    const float* bia = bias + (size_t)e * NTOT;
    #pragma unroll
    for (int mf = 0; mf < 4; mf++) {
        #pragma unroll
        for (int i = 0; i < 4; i++) {
            int m = m0 + wm * 64 + mf * 16 + (lane >> 4) * 4 + i;
            if (m >= c) continue;
            size_t prow = (size_t)(seg + m);
            #pragma unroll
            for (int nf = 0; nf < NF; nf++) {
                int n = n0 + wn * NF * 16 + nf * 16 + (lane & 15);
                float vv = acc[mf][nf][i] + bia[n];
                if (MODE == 0) {
                    vv = 0.5f * vv * (1.0f + erff(vv * 0.70710678118f));
                    ((bf16*)outp)[prow * NTOT + n] = __float2bfloat16(vv);
                } else {
                    ((float*)outp)[prow * NTOT + n] = vv;
                }
            }
        }
    }
}

// ---------------- combine: x[t] += w0*op[p0] + w1*op[p1] ----------------
__global__ __launch_bounds__(256) void combine(const float* __restrict__ op,
                                               const int* __restrict__ inv,
                                               const float* __restrict__ topw,
                                               float* __restrict__ x) {
    int idx = blockIdx.x * blockDim.x + threadIdx.x;
    if (idx >= T_TOK * H_DIM / 4) return;
    int t = idx / (H_DIM / 4);
    int cidx = idx % (H_DIM / 4);
    int p0 = inv[t * 2], p1 = inv[t * 2 + 1];
    float w0 = topw[t * 2], w1 = topw[t * 2 + 1];
    float4 a = ((const float4*)(op + (size_t)p0 * H_DIM))[cidx];
    float4 b = ((const float4*)(op + (size_t)p1 * H_DIM))[cidx];
    float4* xp = (float4*)(x + (size_t)t * H_DIM) + cidx;
    float4 xo = *xp;
    xo.x += w0 * a.x + w1 * b.x;
    xo.y += w0 * a.y + w1 * b.y;
    xo.z += w0 * a.z + w1 * b.z;
    xo.w += w0 * a.w + w1 * b.w;
    *xp = xo;
}

extern "C" void kernel_launch(void* const* d_in, const int* in_sizes, int n_in,
                              void* d_out, int out_size, void* d_ws, size_t ws_size,
                              hipStream_t stream) {
    const int*   ids    = (const int*)d_in[0];
    const float* embed  = (const float*)d_in[1];
    const float* ln_g   = (const float*)d_in[2];
    const float* ln_b   = (const float*)d_in[3];
    const float* gate_w = (const float*)d_in[4];
    const float* gate_b = (const float*)d_in[5];
    const float* fc1_w  = (const float*)d_in[6];
    const float* fc1_b  = (const float*)d_in[7];
    const float* fc2_w  = (const float*)d_in[8];
    const float* fc2_b  = (const float*)d_in[9];

    float* x      = (float*)d_out;
    float* laux   = x + (size_t)T_TOK * H_DIM;
    float* counts = laux + 1;

    const size_t WELEM = (size_t)E_NUM * DF_DIM * H_DIM;   // 18.87M per layer per matrix

    char* ws = (char*)d_ws;
    bf16* wb1   = (bf16*)ws;                                ws += WELEM * sizeof(bf16);
    bf16* wb2   = (bf16*)ws;                                ws += WELEM * sizeof(bf16);
    bf16* h1    = (bf16*)ws;                                ws += (size_t)NPAIR * DF_DIM * sizeof(bf16);
    bf16* flatb = (bf16*)ws;                                ws += (size_t)T_TOK * H_DIM * sizeof(bf16);
    float* op   = (float*)ws;                               ws += (size_t)NPAIR * H_DIM * sizeof(float);
    int*  pair_tok = (int*)ws;                              ws += NPAIR * sizeof(int);
    int*  inv      = (int*)ws;                              ws += NPAIR * sizeof(int);
    int*  topi     = (int*)ws;                              ws += T_TOK * K_TOP * sizeof(int);
    float* topw    = (float*)ws;                            ws += T_TOK * K_TOP * sizeof(float);
    int*  cnt      = (int*)ws;                              ws += E_NUM * sizeof(int);
    int*  offs     = (int*)ws;                              ws += E_NUM * sizeof(int);
    int*  fill     = (int*)ws;                              ws += E_NUM * sizeof(int);
    float* probs   = (float*)ws;                            ws += E_NUM * sizeof(float);

    hipMemsetAsync(laux, 0, 9 * sizeof(float), stream);

    gather_embed<<<(T_TOK * H_DIM / 4 + 255) / 256, 256, 0, stream>>>(ids, embed, x);

    const int n8 = (int)(WELEM / 8);
    for (int l = 0; l < L_NUM; l++) {
        conv_bf16<<<(n8 + 255) / 256, 256, 0, stream>>>(fc1_w + (size_t)l * WELEM, wb1, n8);
        conv_bf16<<<(n8 + 255) / 256, 256, 0, stream>>>(fc2_w + (size_t)l * WELEM, wb2, n8);

        hipMemsetAsync(cnt, 0, 4 * E_NUM * sizeof(int), stream);  // cnt, offs, fill, probs
        ln_gate<<<T_TOK, 256, 0, stream>>>(
            x, ln_g + l * H_DIM, ln_b + l * H_DIM,
            gate_w + (size_t)l * E_NUM * H_DIM, gate_b + l * E_NUM,
            flatb, topi, topw, cnt, probs, counts);
        offsets_laux<<<1, 64, 0, stream>>>(cnt, offs, probs, laux);
        scatter_pairs<<<(T_TOK + 255) / 256, 256, 0, stream>>>(topi, offs, fill, pair_tok, inv);

        dim3 g1(DF_DIM / 128, NPAIR / 128, E_NUM);
        moe_gemm<4, 0, H_DIM, DF_DIM><<<g1, 256, 0, stream>>>(
            flatb, wb1, fc1_b + (size_t)l * E_NUM * DF_DIM, cnt, offs, pair_tok, (void*)h1);

        dim3 g2(H_DIM / 64, NPAIR / 128, E_NUM);
        moe_gemm<2, 1, DF_DIM, H_DIM><<<g2, 256, 0, stream>>>(
            h1, wb2, fc2_b + (size_t)l * E_NUM * H_DIM, cnt, offs, pair_tok, (void*)op);

        combine<<<(T_TOK * H_DIM / 4 + 255) / 256, 256, 0, stream>>>(op, inv, topw, x);
    }
}

// Round 3
// 469.926 us; speedup vs baseline: 5.5241x; 2.0755x over previous
//
#include <hip/hip_runtime.h>
#include <hip/hip_bf16.h>
#include <math.h>

#define T_TOK 2048
#define H_DIM 768
#define E_NUM 8
#define K_TOP 2
#define DF_DIM 3072
#define L_NUM 2
#define LN_EPS 1e-5f
#define NPAIR (T_TOK * K_TOP)

typedef __hip_bfloat16 bf16;
typedef __attribute__((ext_vector_type(8))) short bf16x8;   // 8 bf16 = 4 VGPRs
typedef __attribute__((ext_vector_type(4))) float f32x4;

// ---------------- embedding gather ----------------
__global__ void gather_embed(const int* __restrict__ ids,
                             const float* __restrict__ embed,
                             float* __restrict__ x) {
    int idx = blockIdx.x * blockDim.x + threadIdx.x;
    int total = T_TOK * H_DIM / 4;
    if (idx >= total) return;
    int row = idx / (H_DIM / 4);
    int col = idx % (H_DIM / 4);
    const float4* src = (const float4*)(embed + (size_t)ids[row] * H_DIM);
    ((float4*)(x + (size_t)row * H_DIM))[col] = src[col];
}

// ---------------- LN + gate logits (one block per token, NO atomics) ----------------
__global__ __launch_bounds__(256) void ln_gate(
    const float* __restrict__ x, const float* __restrict__ g, const float* __restrict__ b,
    const float* __restrict__ gw, const float* __restrict__ gb,
    bf16* __restrict__ flat, float* __restrict__ logits_tok)
{
    int t = blockIdx.x;
    int tid = threadIdx.x;
    const float* xr = x + (size_t)t * H_DIM;
    __shared__ float s[H_DIM];
    __shared__ float red[8];

    float v0 = xr[tid], v1 = xr[tid + 256], v2 = xr[tid + 512];
    float sum = v0 + v1 + v2;
    #pragma unroll
    for (int o = 32; o > 0; o >>= 1) sum += __shfl_down(sum, o);
    int wave = tid >> 6, lane = tid & 63;
    if (lane == 0) red[wave] = sum;
    __syncthreads();
    if (tid == 0) red[4] = (red[0] + red[1] + red[2] + red[3]) * (1.0f / H_DIM);
    __syncthreads();
    float mean = red[4];

    float d0 = v0 - mean, d1 = v1 - mean, d2 = v2 - mean;
    float ss = d0 * d0 + d1 * d1 + d2 * d2;
    #pragma unroll
    for (int o = 32; o > 0; o >>= 1) ss += __shfl_down(ss, o);
    if (lane == 0) red[wave] = ss;
    __syncthreads();
    if (tid == 0) red[4] = rsqrtf((red[0] + red[1] + red[2] + red[3]) * (1.0f / H_DIM) + LN_EPS);
    __syncthreads();
    float inv = red[4];

    float n0 = d0 * inv * g[tid]       + b[tid];
    float n1 = d1 * inv * g[tid + 256] + b[tid + 256];
    float n2 = d2 * inv * g[tid + 512] + b[tid + 512];
    s[tid] = n0; s[tid + 256] = n1; s[tid + 512] = n2;
    bf16* fr = flat + (size_t)t * H_DIM;
    fr[tid] = __float2bfloat16(n0);
    fr[tid + 256] = __float2bfloat16(n1);
    fr[tid + 512] = __float2bfloat16(n2);
    __syncthreads();

    // logits: wave w handles experts 2w, 2w+1; lane0 writes
    #pragma unroll
    for (int ei = 0; ei < 2; ++ei) {
        int e = wave * 2 + ei;
        float p = 0.0f;
        const float* wrow = gw + (size_t)e * H_DIM;
        for (int j = lane; j < H_DIM; j += 64) p += s[j] * wrow[j];
        #pragma unroll
        for (int o = 32; o > 0; o >>= 1) p += __shfl_down(p, o);
        if (lane == 0) logits_tok[(size_t)t * E_NUM + e] = p + gb[e];
    }
}

// ---------------- routing: top2 + softmax + reduce + offsets + compaction ----------------
// single block, 1024 threads (T_TOK/1024 = 2 tokens per thread)
__global__ __launch_bounds__(1024) void route(
    const float* __restrict__ logits_tok,
    int* __restrict__ topi, float* __restrict__ topw,
    int* __restrict__ cnt, int* __restrict__ offs,
    int* __restrict__ pair_tok, int* __restrict__ inv,
    float* __restrict__ laux, float* __restrict__ counts_out)
{
    int tid = threadIdx.x;
    float pprob[E_NUM] = {0,0,0,0,0,0,0,0};
    int pcnt[E_NUM] = {0,0,0,0,0,0,0,0};
    int te[2][2];

    #pragma unroll
    for (int it = 0; it < 2; it++) {
        int t = tid + it * 1024;
        const float4* lp = (const float4*)(logits_tok + (size_t)t * E_NUM);
        float4 l0 = lp[0], l1 = lp[1];
        float lg[E_NUM] = {l0.x, l0.y, l0.z, l0.w, l1.x, l1.y, l1.z, l1.w};
        int i0 = 0; float m0 = lg[0];
        #pragma unroll
        for (int e = 1; e < E_NUM; e++) if (lg[e] > m0) { m0 = lg[e]; i0 = e; }
        int i1 = -1; float m1 = -1e30f;
        #pragma unroll
        for (int e = 0; e < E_NUM; e++) if (e != i0 && lg[e] > m1) { m1 = lg[e]; i1 = e; }
        float e1 = expf(m1 - m0);
        float is = 1.0f / (1.0f + e1);
        topi[t * 2] = i0; topi[t * 2 + 1] = i1;
        topw[t * 2] = is; topw[t * 2 + 1] = e1 * is;
        te[it][0] = i0; te[it][1] = i1;
        pcnt[i0]++; pcnt[i1]++;
        float sm = 0.0f, pe[E_NUM];
        #pragma unroll
        for (int e = 0; e < E_NUM; e++) { pe[e] = expf(lg[e] - m0); sm += pe[e]; }
        float isv = 1.0f / sm;
        #pragma unroll
        for (int e = 0; e < E_NUM; e++) pprob[e] += pe[e] * isv;
    }

    // wave reduce (64 lanes)
    #pragma unroll
    for (int o = 32; o > 0; o >>= 1) {
        #pragma unroll
        for (int e = 0; e < E_NUM; e++) {
            pprob[e] += __shfl_down(pprob[e], o);
            pcnt[e]  += __shfl_down(pcnt[e], o);
        }
    }
    __shared__ float wprob[16][E_NUM];
    __shared__ int   wcnt[16][E_NUM];
    __shared__ int   soffs[E_NUM];
    __shared__ int   lfill[E_NUM];
    int wv = tid >> 6, lane = tid & 63;
    if (lane == 0) {
        #pragma unroll
        for (int e = 0; e < E_NUM; e++) { wprob[wv][e] = pprob[e]; wcnt[wv][e] = pcnt[e]; }
    }
    if (tid < E_NUM) lfill[tid] = 0;
    __syncthreads();
    if (tid == 0) {
        float ps[E_NUM]; int cs[E_NUM];
        #pragma unroll
        for (int e = 0; e < E_NUM; e++) {
            float p = 0.0f; int c = 0;
            for (int w = 0; w < 16; w++) { p += wprob[w][e]; c += wcnt[w][e]; }
            ps[e] = p; cs[e] = c;
        }
        int run = 0;
        #pragma unroll
        for (int e = 0; e < E_NUM; e++) { offs[e] = run; soffs[e] = run; cnt[e] = cs[e]; run += cs[e]; }
        float la = 0.0f;
        #pragma unroll
        for (int e = 0; e < E_NUM; e++) { float p = ps[e] * (1.0f / T_TOK); la += p * p; }
        laux[0] += la * E_NUM;
        #pragma unroll
        for (int e = 0; e < E_NUM; e++) counts_out[e] += (float)cs[e];
    }
    __syncthreads();

    // compaction via LDS fill counters
    #pragma unroll
    for (int it = 0; it < 2; it++) {
        int t = tid + it * 1024;
        #pragma unroll
        for (int k = 0; k < K_TOP; k++) {
            int e = te[it][k];
            int pos = atomicAdd(&lfill[e], 1);
            int p = soffs[e] + pos;
            pair_tok[p] = t;
            inv[t * 2 + k] = p;
        }
    }
}

// ---------------- MFMA grouped GEMM (weights loaded f32, converted in-register) ----
// MODE 0 (fc1): A = flat[pair_tok[row]] (bf16), out = h1 bf16 with bias+GELU
// MODE 1 (fc2): A = h1[seg+row] (bf16),        out = out_pairs f32 with bias
// tile: BM=128 x BN=32*NF, BK=32. 4 waves as 2(M) x 2(N), wave = 64 x 16*NF.
template<int NF, int MODE, int KDIM, int NTOT>
__global__ __launch_bounds__(256) void moe_gemm(
    const bf16* __restrict__ Abase, const float* __restrict__ Wf,
    const float* __restrict__ bias,
    const int* __restrict__ cnt, const int* __restrict__ offs,
    const int* __restrict__ pair_tok, void* __restrict__ outp)
{
    constexpr int BM = 128;
    constexpr int BN = 32 * NF;
    constexpr int NISS = (BM + BN) / 16;   // 1KB staging issues per K-step
    constexpr int IPW  = NISS / 4;         // issues per wave

    int e = blockIdx.z;
    int c = cnt[e];
    int m0 = blockIdx.y * BM;
    if (m0 >= c) return;
    int n0 = blockIdx.x * BN;
    int seg = offs[e];
    const float* W = Wf + (size_t)e * NTOT * KDIM;

    __shared__ char smem[(BM + BN) * 64];  // A tile [128][32]bf16 + B tile [BN][32]bf16, swizzled

    int tid = threadIdx.x;
    int lane = tid & 63, wv = tid >> 6;

    // ---- per-lane staging setup (fixed across K loop) ----
    const bf16*  gA[IPW];
    const float* gW[IPW];
    bool isA[IPW];
    int ldsoff[IPW];
    #pragma unroll
    for (int q = 0; q < IPW; q++) {
        int j = wv + q * 4;                // issue id 0..NISS-1
        int rloc = lane >> 2;              // 16 rows per issue
        int kb = lane & 3;                 // 4 chunks of 8 elems per row
        int row, base;
        gA[q] = nullptr; gW[q] = nullptr;
        if (j < 8) {                       // A rows (bf16)
            row = j * 16 + rloc;
            int m = m0 + row;
            int mm = (m < c) ? m : (c - 1);
            if (MODE == 0)
                gA[q] = Abase + (size_t)pair_tok[seg + mm] * KDIM + kb * 8;
            else
                gA[q] = Abase + (size_t)(seg + mm) * KDIM + kb * 8;
            base = 0;
            isA[q] = true;
        } else {                           // B rows (f32 weights)
            row = (j - 8) * 16 + rloc;
            gW[q] = W + (size_t)(n0 + row) * KDIM + kb * 8;
            base = BM * 64;
            isA[q] = false;
        }
        int line = row >> 1;
        int cc = ((row & 1) << 2) | kb;
        ldsoff[q] = base + line * 128 + ((cc ^ (line & 7)) << 4);
    }

    // ---- per-lane fragment read offsets ----
    int wm = wv >> 1, wn = wv & 1;
    int aoff[4], boff[NF];
    {
        int kb = lane >> 4;
        #pragma unroll
        for (int mf = 0; mf < 4; mf++) {
            int row = wm * 64 + mf * 16 + (lane & 15);
            int line = row >> 1;
            int cc = ((row & 1) << 2) | kb;
            aoff[mf] = line * 128 + ((cc ^ (line & 7)) << 4);
        }
        #pragma unroll
        for (int nf = 0; nf < NF; nf++) {
            int row = wn * NF * 16 + nf * 16 + (lane & 15);
            int line = row >> 1;
            int cc = ((row & 1) << 2) | kb;
            boff[nf] = BM * 64 + line * 128 + ((cc ^ (line & 7)) << 4);
        }
    }

    f32x4 acc[4][NF];
    #pragma unroll
    for (int i = 0; i < 4; i++)
        #pragma unroll
        for (int j = 0; j < NF; j++) acc[i][j] = (f32x4){0.f, 0.f, 0.f, 0.f};

    // ---- K loop (2-barrier) ----
    for (int k0 = 0; k0 < KDIM; k0 += 32) {
        uint4 v[IPW];
        #pragma unroll
        for (int q = 0; q < IPW; q++) {
            if (isA[q]) {
                v[q] = *(const uint4*)(gA[q] + k0);
            } else {
                const float4* p = (const float4*)(gW[q] + k0);
                float4 a = p[0], bb = p[1];
                union { bf16 h[8]; uint4 u; } pk;
                pk.h[0] = __float2bfloat16(a.x);  pk.h[1] = __float2bfloat16(a.y);
                pk.h[2] = __float2bfloat16(a.z);  pk.h[3] = __float2bfloat16(a.w);
                pk.h[4] = __float2bfloat16(bb.x); pk.h[5] = __float2bfloat16(bb.y);
                pk.h[6] = __float2bfloat16(bb.z); pk.h[7] = __float2bfloat16(bb.w);
                v[q] = pk.u;
            }
        }
        #pragma unroll
        for (int q = 0; q < IPW; q++) *(uint4*)(smem + ldsoff[q]) = v[q];
        __syncthreads();
        bf16x8 af[4], bfr[NF];
        #pragma unroll
        for (int mf = 0; mf < 4; mf++) af[mf] = *(const bf16x8*)(smem + aoff[mf]);
        #pragma unroll
        for (int nf = 0; nf < NF; nf++) bfr[nf] = *(const bf16x8*)(smem + boff[nf]);
        #pragma unroll
        for (int mf = 0; mf < 4; mf++)
            #pragma unroll
            for (int nf = 0; nf < NF; nf++)
                acc[mf][nf] = __builtin_amdgcn_mfma_f32_16x16x32_bf16(af[mf], bfr[nf], acc[mf][nf], 0, 0, 0);
        __syncthreads();
    }

    // ---- epilogue (C layout: col = lane&15, row = (lane>>4)*4 + i) ----
    const float* bia = bias + (size_t)e * NTOT;
    #pragma unroll
    for (int mf = 0; mf < 4; mf++) {
        #pragma unroll
        for (int i = 0; i < 4; i++) {
            int m = m0 + wm * 64 + mf * 16 + (lane >> 4) * 4 + i;
            if (m >= c) continue;
            size_t prow = (size_t)(seg + m);
            #pragma unroll
            for (int nf = 0; nf < NF; nf++) {
                int n = n0 + wn * NF * 16 + nf * 16 + (lane & 15);
                float vv = acc[mf][nf][i] + bia[n];
                if (MODE == 0) {
                    vv = 0.5f * vv * (1.0f + erff(vv * 0.70710678118f));
                    ((bf16*)outp)[prow * NTOT + n] = __float2bfloat16(vv);
                } else {
                    ((float*)outp)[prow * NTOT + n] = vv;
                }
            }
        }
    }
}

// ---------------- combine: x[t] += w0*op[p0] + w1*op[p1] ----------------
__global__ __launch_bounds__(256) void combine(const float* __restrict__ op,
                                               const int* __restrict__ inv,
                                               const float* __restrict__ topw,
                                               float* __restrict__ x) {
    int idx = blockIdx.x * blockDim.x + threadIdx.x;
    if (idx >= T_TOK * H_DIM / 4) return;
    int t = idx / (H_DIM / 4);
    int cidx = idx % (H_DIM / 4);
    int p0 = inv[t * 2], p1 = inv[t * 2 + 1];
    float w0 = topw[t * 2], w1 = topw[t * 2 + 1];
    float4 a = ((const float4*)(op + (size_t)p0 * H_DIM))[cidx];
    float4 b = ((const float4*)(op + (size_t)p1 * H_DIM))[cidx];
    float4* xp = (float4*)(x + (size_t)t * H_DIM) + cidx;
    float4 xo = *xp;
    xo.x += w0 * a.x + w1 * b.x;
    xo.y += w0 * a.y + w1 * b.y;
    xo.z += w0 * a.z + w1 * b.z;
    xo.w += w0 * a.w + w1 * b.w;
    *xp = xo;
}

extern "C" void kernel_launch(void* const* d_in, const int* in_sizes, int n_in,
                              void* d_out, int out_size, void* d_ws, size_t ws_size,
                              hipStream_t stream) {
    const int*   ids    = (const int*)d_in[0];
    const float* embed  = (const float*)d_in[1];
    const float* ln_g   = (const float*)d_in[2];
    const float* ln_b   = (const float*)d_in[3];
    const float* gate_w = (const float*)d_in[4];
    const float* gate_b = (const float*)d_in[5];
    const float* fc1_w  = (const float*)d_in[6];
    const float* fc1_b  = (const float*)d_in[7];
    const float* fc2_w  = (const float*)d_in[8];
    const float* fc2_b  = (const float*)d_in[9];

    float* x      = (float*)d_out;
    float* laux   = x + (size_t)T_TOK * H_DIM;
    float* counts = laux + 1;

    const size_t WELEM = (size_t)E_NUM * DF_DIM * H_DIM;

    char* ws = (char*)d_ws;
    bf16* h1    = (bf16*)ws;            ws += (size_t)NPAIR * DF_DIM * sizeof(bf16);
    bf16* flatb = (bf16*)ws;            ws += (size_t)T_TOK * H_DIM * sizeof(bf16);
    float* op   = (float*)ws;           ws += (size_t)NPAIR * H_DIM * sizeof(float);
    float* logits_tok = (float*)ws;     ws += (size_t)T_TOK * E_NUM * sizeof(float);
    int*  pair_tok = (int*)ws;          ws += NPAIR * sizeof(int);
    int*  inv      = (int*)ws;          ws += NPAIR * sizeof(int);
    int*  topi     = (int*)ws;          ws += T_TOK * K_TOP * sizeof(int);
    float* topw    = (float*)ws;        ws += T_TOK * K_TOP * sizeof(float);
    int*  cnt      = (int*)ws;          ws += E_NUM * sizeof(int);
    int*  offs     = (int*)ws;          ws += E_NUM * sizeof(int);

    hipMemsetAsync(laux, 0, 9 * sizeof(float), stream);

    gather_embed<<<(T_TOK * H_DIM / 4 + 255) / 256, 256, 0, stream>>>(ids, embed, x);

    for (int l = 0; l < L_NUM; l++) {
        ln_gate<<<T_TOK, 256, 0, stream>>>(
            x, ln_g + l * H_DIM, ln_b + l * H_DIM,
            gate_w + (size_t)l * E_NUM * H_DIM, gate_b + l * E_NUM,
            flatb, logits_tok);
        route<<<1, 1024, 0, stream>>>(logits_tok, topi, topw, cnt, offs,
                                      pair_tok, inv, laux, counts);

        dim3 g1(DF_DIM / 128, NPAIR / 128, E_NUM);
        moe_gemm<4, 0, H_DIM, DF_DIM><<<g1, 256, 0, stream>>>(
            flatb, fc1_w + (size_t)l * WELEM,
            fc1_b + (size_t)l * E_NUM * DF_DIM, cnt, offs, pair_tok, (void*)h1);

        dim3 g2(H_DIM / 64, NPAIR / 128, E_NUM);
        moe_gemm<2, 1, DF_DIM, H_DIM><<<g2, 256, 0, stream>>>(
            h1, fc2_w + (size_t)l * WELEM,
            fc2_b + (size_t)l * E_NUM * H_DIM, cnt, offs, pair_tok, (void*)op);

        combine<<<(T_TOK * H_DIM / 4 + 255) / 256, 256, 0, stream>>>(op, inv, topw, x);
    }
}